// Round 9
// baseline (338.320 us; speedup 1.0000x reference)
//
#include <hip/hip_runtime.h>
#include <math.h>
#include <type_traits>

typedef unsigned short u16;
typedef __attribute__((ext_vector_type(8))) short bf16x8;
typedef __attribute__((ext_vector_type(4))) float f32x4;

// Problem constants (fixed by the reference)
#define B_  2
#define S_  2048
#define D_  2048
#define H_  16
#define HD_ 128
#define L_  512
constexpr float EPS   = 1e-5f;
constexpr float SCALE = 0.08838834764831845f;           // 1/sqrt(128)
constexpr float SCALE_L2E = 0.12751701840172524f;       // SCALE * log2(e)
constexpr float SHIFT2    = -11.541560327111707f;       // -8 * log2(e)

__device__ __forceinline__ u16 f2bf(float x) {
    unsigned u = __float_as_uint(x);
    u += 0x7fffu + ((u >> 16) & 1u);   // round-to-nearest-even
    return (u16)(u >> 16);
}
__device__ __forceinline__ float bf2f(u16 v) {
    return __uint_as_float(((unsigned)v) << 16);
}

// async global->LDS, 16 B per lane; LDS dest = lptr + lane*16 (wave-uniform base)
__device__ __forceinline__ void gl_lds16(const u16* g, u16* l) {
    __builtin_amdgcn_global_load_lds(
        (const __attribute__((address_space(1))) unsigned int*)g,
        (__attribute__((address_space(3))) unsigned int*)l, 16, 0, 0);
}

// ---------------------------------------------------------------------------
// bf16 MFMA GEMM (m97 structure): C[M,N] = A[M,K] @ Bt[N,K]^T + bias[N]
// BM=128 x BN tile, BK=32, 256 thr, 4 waves (2x2), per-wave 64 x BN/2.
// BN=64 for small-N shapes (2+ blocks/CU).  lda/ldc: A/C row strides.
// Bias: n < nsplit ? biasA[n] : biasB[n-nsplit].
// Used for: down-projection (BN=64) and out-projection (BN=128, fp32 out).
// ---------------------------------------------------------------------------
template <typename OutT, int BN>
__global__ __launch_bounds__(256)
void gemm_mfma_kernel(const u16* __restrict__ A, const u16* __restrict__ Bt,
                      const float* __restrict__ biasA,
                      const float* __restrict__ biasB, OutT* __restrict__ C,
                      int M, int N, int K, int lda, int ldc, int nsplit) {
    constexpr int NJ = BN / 32;            // per-wave j-tiles (BN/2 cols / 16)
    __shared__ __align__(16) u16 As[128 * 32];
    __shared__ __align__(16) u16 Bs[BN * 32];

    const int tid  = threadIdx.x;
    const int wave = tid >> 6, lane = tid & 63;
    const int l15  = lane & 15, g = lane >> 4;
    const int wm   = wave >> 1, wn = wave & 1;
    const int m0   = blockIdx.y * 128, n0 = blockIdx.x * BN;

    const int sr = lane >> 2;       // staging row within 16-row group
    const int sc = lane & 3;        // chunk slot
    const int swz = (l15 >> 1) & 3; // read-side swizzle key

    f32x4 acc[4][NJ];
#pragma unroll
    for (int i = 0; i < 4; ++i)
#pragma unroll
        for (int j = 0; j < NJ; ++j) acc[i][j] = (f32x4)0.f;

    for (int k0 = 0; k0 < K; k0 += 32) {
#pragma unroll
        for (int t = 0; t < 2; ++t) {   // A: 128 rows
            const int r  = wave * 32 + t * 16 + sr;
            const int c  = sc ^ ((r >> 1) & 3);
            gl_lds16(A + (size_t)(m0 + r) * lda + k0 + c * 8,
                     &As[(wave * 32 + t * 16) * 32]);
        }
#pragma unroll
        for (int t = 0; t < BN / 64; ++t) {  // B: BN rows
            const int r  = wave * (BN / 4) + t * 16 + sr;
            const int c  = sc ^ ((r >> 1) & 3);
            gl_lds16(Bt + (size_t)(n0 + r) * K + k0 + c * 8,
                     &Bs[(wave * (BN / 4) + t * 16) * 32]);
        }
        __syncthreads();

        bf16x8 af[4], bfr[NJ];
#pragma unroll
        for (int i = 0; i < 4; ++i) {
            const int ra = wm * 64 + i * 16 + l15;
            af[i]  = *(const bf16x8*)&As[ra * 32 + (g ^ swz) * 8];
        }
#pragma unroll
        for (int j = 0; j < NJ; ++j) {
            const int rb = wn * (BN / 2) + j * 16 + l15;
            bfr[j] = *(const bf16x8*)&Bs[rb * 32 + (g ^ swz) * 8];
        }
#pragma unroll
        for (int i = 0; i < 4; ++i)
#pragma unroll
            for (int j = 0; j < NJ; ++j)
                acc[i][j] = __builtin_amdgcn_mfma_f32_16x16x32_bf16(
                    af[i], bfr[j], acc[i][j], 0, 0, 0);
        __syncthreads();
    }

#pragma unroll
    for (int j = 0; j < NJ; ++j) {
        const int n  = n0 + wn * (BN / 2) + j * 16 + l15;
        const float bv = (n < nsplit) ? biasA[n] : biasB[n - nsplit];
#pragma unroll
        for (int i = 0; i < 4; ++i) {
            const int mb = m0 + wm * 64 + i * 16 + g * 4;
#pragma unroll
            for (int r = 0; r < 4; ++r) {
                float v = acc[i][j][r] + bv;
                if constexpr (std::is_same_v<OutT, float>)
                    C[(size_t)(mb + r) * ldc + n] = v;
                else
                    C[(size_t)(mb + r) * ldc + n] = f2bf(v);
            }
        }
    }
}

// ---------------------------------------------------------------------------
// Merged up-projection GEMM (kv-up + q-up in ONE launch). Block-uniform
// dispatch on x: x<32 kv-up (K-half -> k_bf, V-half -> vt transposed);
// x>=32 q-up -> q_bf. Both read lat with lda = 2L.
// ---------------------------------------------------------------------------
__global__ __launch_bounds__(256)
void up_gemm_kernel(const u16* __restrict__ lat,
                    const u16* __restrict__ wkvu_t, const u16* __restrict__ wqu_t,
                    const float* __restrict__ bkv_up, const float* __restrict__ bq_up,
                    u16* __restrict__ k_bf, u16* __restrict__ vt,
                    u16* __restrict__ q_bf) {
    __shared__ __align__(16) u16 As[128 * 32];
    __shared__ __align__(16) u16 Bs[128 * 32];

    const int bx    = blockIdx.x;
    const bool iskv = bx < 32;
    const u16* A    = iskv ? lat + L_ : lat;
    const u16* Bt   = iskv ? wkvu_t : wqu_t;
    const float* bias = iskv ? bkv_up : bq_up;
    const int n0    = (iskv ? bx : bx - 32) * 128;
    const int m0    = blockIdx.y * 128;
    constexpr int K = L_, lda = 2 * L_;

    const int tid  = threadIdx.x;
    const int wave = tid >> 6, lane = tid & 63;
    const int l15  = lane & 15, g = lane >> 4;
    const int wm   = wave >> 1, wn = wave & 1;

    const int sr = lane >> 2;
    const int sc = lane & 3;
    const int swz = (l15 >> 1) & 3;

    f32x4 acc[4][4];
#pragma unroll
    for (int i = 0; i < 4; ++i)
#pragma unroll
        for (int j = 0; j < 4; ++j) acc[i][j] = (f32x4)0.f;

    for (int k0 = 0; k0 < K; k0 += 32) {
#pragma unroll
        for (int t = 0; t < 2; ++t) {
            const int r  = wave * 32 + t * 16 + sr;
            const int c  = sc ^ ((r >> 1) & 3);
            gl_lds16(A  + (size_t)(m0 + r) * lda + k0 + c * 8,
                     &As[(wave * 32 + t * 16) * 32]);
            gl_lds16(Bt + (size_t)(n0 + r) * K + k0 + c * 8,
                     &Bs[(wave * 32 + t * 16) * 32]);
        }
        __syncthreads();

        bf16x8 af[4], bfr[4];
#pragma unroll
        for (int i = 0; i < 4; ++i) {
            const int ra = wm * 64 + i * 16 + l15;
            af[i]  = *(const bf16x8*)&As[ra * 32 + (g ^ swz) * 8];
            const int rb = wn * 64 + i * 16 + l15;
            bfr[i] = *(const bf16x8*)&Bs[rb * 32 + (g ^ swz) * 8];
        }
#pragma unroll
        for (int i = 0; i < 4; ++i)
#pragma unroll
            for (int j = 0; j < 4; ++j)
                acc[i][j] = __builtin_amdgcn_mfma_f32_16x16x32_bf16(
                    af[i], bfr[j], acc[i][j], 0, 0, 0);
        __syncthreads();
    }

    const bool vstore = iskv && (n0 >= D_);   // block-uniform
#pragma unroll
    for (int j = 0; j < 4; ++j) {
        const int n  = n0 + wn * 64 + j * 16 + l15;
        const float bv = bias[n];
        if (vstore) {
            // transposed V store: vt[(b*H+h)*HD+d][s], s = m (4 consecutive)
            const int dg = n - D_;
            const int hh = dg >> 7, dd = dg & 127;
            u16* vrow = vt + ((size_t)(((m0 >> 11) * H_ + hh) * HD_ + dd)) * S_;
#pragma unroll
            for (int i = 0; i < 4; ++i) {
                const int mb = m0 + wm * 64 + i * 16 + g * 4;
                ushort4 o;
                o.x = f2bf(acc[i][j][0] + bv);
                o.y = f2bf(acc[i][j][1] + bv);
                o.z = f2bf(acc[i][j][2] + bv);
                o.w = f2bf(acc[i][j][3] + bv);
                *(ushort4*)&vrow[mb & (S_ - 1)] = o;
            }
        } else {
            u16* C = iskv ? k_bf : q_bf;
#pragma unroll
            for (int i = 0; i < 4; ++i) {
                const int mb = m0 + wm * 64 + i * 16 + g * 4;
#pragma unroll
                for (int r = 0; r < 4; ++r)
                    C[(size_t)(mb + r) * D_ + n] = f2bf(acc[i][j][r] + bv);
            }
        }
    }
}

// ---------------------------------------------------------------------------
// Prep: all 5 weight transposes + x fp32->bf16 cast in ONE launch.
// ---------------------------------------------------------------------------
__global__ __launch_bounds__(256)
void prep_kernel(const float* __restrict__ wqd,  const float* __restrict__ wkvd,
                 const float* __restrict__ wqu,  const float* __restrict__ wkvu,
                 const float* __restrict__ wo,   const float* __restrict__ x,
                 u16* __restrict__ wd_t,  u16* __restrict__ wqu_t,
                 u16* __restrict__ wkvu_t, u16* __restrict__ wout_t,
                 u16* __restrict__ x_bf) {
    int bid = blockIdx.x;
    if (bid >= 2304) {   // x cast: 8192 blocks x 256 thr x float4
        const int i = (bid - 2304) * 256 + threadIdx.x;
        float4 f = ((const float4*)x)[i];
        ushort4 o;
        o.x = f2bf(f.x); o.y = f2bf(f.y); o.z = f2bf(f.z); o.w = f2bf(f.w);
        ((ushort4*)x_bf)[i] = o;
        return;
    }
    const float* W; u16* Wt; int K, N;
    if (bid < 256)       { W = wqd;  Wt = wd_t;                      K = 2048; N = 512; }
    else if (bid < 512)  { W = wkvd; Wt = wd_t + (size_t)512 * 2048; K = 2048; N = 512;  bid -= 256; }
    else if (bid < 768)  { W = wqu;  Wt = wqu_t;                     K = 512;  N = 2048; bid -= 512; }
    else if (bid < 1280) { W = wkvu; Wt = wkvu_t;                    K = 512;  N = 4096; bid -= 768; }
    else                 { W = wo;   Wt = wout_t;                    K = 2048; N = 2048; bid -= 1280; }
    const int nblk = N / 64;
    const int n0 = (bid % nblk) * 64, k0 = (bid / nblk) * 64;

    __shared__ u16 T[64][72];
    const int t = threadIdx.x;
    {
        const int kr = t >> 2, nc = (t & 3) * 16;
#pragma unroll
        for (int v = 0; v < 4; ++v) {
            float4 f = *(const float4*)&W[(size_t)(k0 + kr) * N + n0 + nc + v * 4];
            T[nc + v * 4 + 0][kr] = f2bf(f.x);
            T[nc + v * 4 + 1][kr] = f2bf(f.y);
            T[nc + v * 4 + 2][kr] = f2bf(f.z);
            T[nc + v * 4 + 3][kr] = f2bf(f.w);
        }
    }
    __syncthreads();
    {
        const int nr = t >> 2, kc = (t & 3) * 16;
        union { u16 u[16]; uint4 q[2]; } o;
#pragma unroll
        for (int i = 0; i < 16; ++i) o.u[i] = T[nr][kc + i];
        uint4* dst = (uint4*)&Wt[(size_t)(n0 + nr) * K + k0 + kc];
        dst[0] = o.q[0]; dst[1] = o.q[1];
    }
}

// ---------------------------------------------------------------------------
// In-place bf16 row LayerNorm over the fused latent [M][1024].
// ---------------------------------------------------------------------------
__global__ __launch_bounds__(256)
void layernorm_fused_kernel(u16* __restrict__ buf,
                            const float* __restrict__ gq,
                            const float* __restrict__ bq,
                            const float* __restrict__ gkv,
                            const float* __restrict__ bkv) {
    const int r    = blockIdx.x;
    const int half = r & 1;
    u16* p = buf + (size_t)(r >> 1) * 1024 + half * 512;
    const float* g    = half ? gkv : gq;
    const float* bvec = half ? bkv : bq;
    const int tid = threadIdx.x;

    float x0 = bf2f(p[tid]), x1 = bf2f(p[tid + 256]);
    float s  = x0 + x1;
    float sq = x0 * x0 + x1 * x1;

    __shared__ float red[8];
    __shared__ float stats[2];

#pragma unroll
    for (int off = 32; off; off >>= 1) {
        s  += __shfl_down(s, off);
        sq += __shfl_down(sq, off);
    }
    const int wave = tid >> 6;
    if ((tid & 63) == 0) { red[wave] = s; red[wave + 4] = sq; }
    __syncthreads();
    if (tid == 0) {
        float ts = red[0] + red[1] + red[2] + red[3];
        float tq = red[4] + red[5] + red[6] + red[7];
        float mean = ts / (float)L_;
        float var  = tq / (float)L_ - mean * mean;
        stats[0] = mean;
        stats[1] = rsqrtf(var + EPS);
    }
    __syncthreads();
    const float mean = stats[0], rstd = stats[1];
    p[tid]       = f2bf((x0 - mean) * rstd * g[tid]       + bvec[tid]);
    p[tid + 256] = f2bf((x1 - mean) * rstd * g[tid + 256] + bvec[tid + 256]);
}

// ---------------------------------------------------------------------------
// Flash attention v10: 3 blocks/CU via LDS diet (73KB -> 53KB).
// Post-mortem of v9 (71.8us, MfmaUtil 20.9, VALUBusy 34.8, Occ 19.9): stall-
// dominated; ~2600 cy/tile vs ~165cy MFMA + ~400cy VALU per SIMD. TLP is the
// lever: 2 blocks/CU (LDS-capped) -> 3 (needs <=54.6KB).
//  - V single-buffered (-16KB): staged at TOP of tile t, consumed after a
//    mid-tile barrier (QK+softmax ~1000cy of latency cover). K keeps dbuf +
//    top-of-tile prefetch. End-of-tile barrier protects V WAR.
//  - Pl halved to 32 keys (PPITCH 40, rows 16B-aligned, -4KB): PV in two
//    32-key halves reusing one per-wave slice. Same-wave DS ops are in-order
//    (LDS returns in order) and compiler preserves alias order, so half1
//    writes cannot pass the half0 pf read.
//  - exp2 folding: P = exp2(fma(s, SCALE*log2e, -8*log2e)) -- kills 16
//    v_mul/tile (v_exp_f32 is 2^x natively).
// LDS: 32768 (K dbuf) + 16384 (V) + 5120 (Pl) = 54272 <= 54613 -> 3 blk/CU.
// grid: (S/64)*H*B = 1024 blocks, heavy q-groups first.
// ---------------------------------------------------------------------------
#define PPITCH 40

__global__ __launch_bounds__(256)
void flash_attn_kernel(const u16* __restrict__ qbf, const u16* __restrict__ kbf,
                       const u16* __restrict__ vt,
                       const unsigned char* __restrict__ mask,
                       u16* __restrict__ out) {
    const int x    = blockIdx.x;
    const int qgrp = (S_ / 64 - 1) - (x >> 5);   // heavy blocks first
    const int hb   = x & 31;
    const int h    = hb >> 1, b = hb & 1;
    const int tid  = threadIdx.x;
    const int wave = tid >> 6, lane = tid & 63;
    const int l15  = lane & 15, g = lane >> 4;
    const int q0   = qgrp * 64 + wave * 16;      // this wave's 16 queries

    __shared__ __align__(16) u16 Ks[2][64][128];   // 32 KB, key x d (dbuf)
    __shared__ __align__(16) u16 Vs[128][64];      // 16 KB, d x key (single)
    __shared__ __align__(16) u16 Pl[4][16][PPITCH]; // 5 KB, 32-key half slice

    const u16* kbase = kbf + (size_t)b * S_ * D_ + h * HD_;
    const u16* vbase = vt + (size_t)((b * H_ + h) * HD_) * S_;
    const unsigned char* mbase = mask + b * S_;

    const int kr_l = lane >> 4;          // K: row within 4-row chunk
    const int kb_l = (lane & 15) * 16;   // K: byte within 256B row
    const int vr_l = lane >> 3;          // V: row within 8-row chunk
    const int vb_l = (lane & 7) * 16;    // V: byte within 128B row

    auto STAGE_K = [&](int bi, int k0s) {
#pragma unroll
        for (int j = 0; j < 4; ++j) {
            const int rr = wave * 16 + j * 4 + kr_l;          // key row 0..63
            gl_lds16(kbase + (size_t)(k0s + rr) * D_ +
                         ((kb_l ^ ((rr & 7) << 4)) >> 1),
                     &Ks[bi][wave * 16 + j * 4][0]);
        }
    };
    auto STAGE_V = [&](int k0s) {
#pragma unroll
        for (int j = 0; j < 4; ++j) {
            const int rv = wave * 32 + j * 8 + vr_l;          // d row 0..127
            gl_lds16(vbase + (size_t)rv * S_ + k0s +
                         ((vb_l ^ ((rv & 7) << 4)) >> 1),
                     &Vs[wave * 32 + j * 8][0]);
        }
    };

    // Q fragments (A-operand): row l15, k = c*32 + g*8 + j
    bf16x8 qf[4];
#pragma unroll
    for (int c = 0; c < 4; ++c)
        qf[c] = *(const bf16x8*)(qbf +
            (size_t)(b * S_ + q0 + l15) * D_ + h * HD_ + c * 32 + g * 8);

    // all-ones bf16 B-fragment for the row-sum MFMA
    bf16x8 ones;
#pragma unroll
    for (int j = 0; j < 8; ++j) ones[j] = (short)0x3f80;  // 1.0f in bf16

    f32x4 o[8];
#pragma unroll
    for (int i = 0; i < 8; ++i) o[i] = (f32x4)0.f;
    f32x4 osum = (f32x4)0.f;

    const int qb  = q0 + 4 * g;
    const int ksw = (l15 & 7) << 4;        // read-side XOR key (bytes)
    const int nt  = qgrp + 1;              // uniform across the block

    STAGE_K(0, 0);
    __syncthreads();   // K0 ready

    for (int kt = 0; kt < nt; ++kt) {
        const int k0  = kt * 64;
        const int cur = kt & 1;
        STAGE_V(k0);                                 // V for CURRENT tile
        if (kt + 1 < nt) STAGE_K(cur ^ 1, k0 + 64);  // K prefetch (dbuf)

        // padding mask -> additive bias (static shift -8, exp2 domain)
        float nb[4];
#pragma unroll
        for (int cc = 0; cc < 4; ++cc)
            nb[cc] = mbase[k0 + cc * 16 + l15] ? -INFINITY : SHIFT2;

        // QK^T from LDS: 4 independent accumulation chains of 4 MFMAs
        f32x4 s[4];
#pragma unroll
        for (int cc = 0; cc < 4; ++cc) {
            bf16x8 kf[4];
#pragma unroll
            for (int c = 0; c < 4; ++c)
                kf[c] = *(const bf16x8*)&Ks[cur][cc * 16 + l15]
                    [((c * 64 + g * 16) ^ ksw) >> 1];
            f32x4 t = (f32x4)0.f;
#pragma unroll
            for (int c = 0; c < 4; ++c)
                t = __builtin_amdgcn_mfma_f32_16x16x32_bf16(qf[c], kf[c], t, 0, 0, 0);
            s[cc] = t;
        }

        // scale + shift/padding in one FMA per score (exp2 domain)
#pragma unroll
        for (int cc = 0; cc < 4; ++cc)
#pragma unroll
            for (int r = 0; r < 4; ++r)
                s[cc][r] = fmaf(s[cc][r], SCALE_L2E, nb[cc]);

        // causal mask: only the final tile contains keys > query
        if (kt == nt - 1) {
#pragma unroll
            for (int cc = 0; cc < 4; ++cc) {
                const int kk = k0 + cc * 16 + l15;
#pragma unroll
                for (int r = 0; r < 4; ++r)
                    if (kk > qb + r) s[cc][r] = -INFINITY;
            }
        }

        __syncthreads();   // V(kt) ready; drains K(kt+1) early (>=QK-phase old)

        // ---- PV half 0: keys 0..31 ----
#pragma unroll
        for (int cc = 0; cc < 2; ++cc)
#pragma unroll
            for (int r = 0; r < 4; ++r)
                Pl[wave][4 * g + r][cc * 16 + l15] = f2bf(exp2f(s[cc][r]));
        const bf16x8 pf0 = *(const bf16x8*)&Pl[wave][l15][g * 8];
#pragma unroll
        for (int i = 0; i < 8; ++i) {
            bf16x8 vf = *(const bf16x8*)&Vs[16 * i + l15][((g * 16) ^ ksw) >> 1];
            o[i] = __builtin_amdgcn_mfma_f32_16x16x32_bf16(pf0, vf, o[i], 0, 0, 0);
        }
        osum = __builtin_amdgcn_mfma_f32_16x16x32_bf16(pf0, ones, osum, 0, 0, 0);

        // ---- PV half 1: keys 32..63 (reuses the Pl slice; same-wave DS
        //      ops are in-order so these writes cannot pass the pf0 read) ----
#pragma unroll
        for (int cc = 2; cc < 4; ++cc)
#pragma unroll
            for (int r = 0; r < 4; ++r)
                Pl[wave][4 * g + r][(cc - 2) * 16 + l15] = f2bf(exp2f(s[cc][r]));
        const bf16x8 pf1 = *(const bf16x8*)&Pl[wave][l15][g * 8];
#pragma unroll
        for (int i = 0; i < 8; ++i) {
            bf16x8 vf = *(const bf16x8*)&Vs[16 * i + l15][((g * 16 + 64) ^ ksw) >> 1];
            o[i] = __builtin_amdgcn_mfma_f32_16x16x32_bf16(pf1, vf, o[i], 0, 0, 0);
        }
        osum = __builtin_amdgcn_mfma_f32_16x16x32_bf16(pf1, ones, osum, 0, 0, 0);

        __syncthreads();   // all PV reads done -> next STAGE_V may overwrite
    }

    // epilogue: normalize by osum (row-sum of bf16 P, same rows as o) + store
    float inv[4];
#pragma unroll
    for (int r = 0; r < 4; ++r) inv[r] = 1.0f / osum[r];
#pragma unroll
    for (int i = 0; i < 8; ++i)
#pragma unroll
        for (int r = 0; r < 4; ++r)
            out[(size_t)(b * S_ + q0 + 4 * g + r) * D_ +
                h * HD_ + 16 * i + l15] = f2bf(o[i][r] * inv[r]);
}

// ---------------------------------------------------------------------------
extern "C" void kernel_launch(void* const* d_in, const int* in_sizes, int n_in,
                              void* d_out, int out_size, void* d_ws, size_t ws_size,
                              hipStream_t stream) {
    const float* x        = (const float*)d_in[0];
    const unsigned char* mask = (const unsigned char*)d_in[1];
    const float* wq_down  = (const float*)d_in[2];
    const float* bq_down  = (const float*)d_in[3];
    const float* gq_ln    = (const float*)d_in[4];
    const float* bq_ln    = (const float*)d_in[5];
    const float* wq_up    = (const float*)d_in[6];
    const float* bq_up    = (const float*)d_in[7];
    const float* wkv_down = (const float*)d_in[8];
    const float* bkv_down = (const float*)d_in[9];
    const float* gkv_ln   = (const float*)d_in[10];
    const float* bkv_ln   = (const float*)d_in[11];
    const float* wkv_up   = (const float*)d_in[12];
    const float* bkv_up   = (const float*)d_in[13];
    const float* w_out    = (const float*)d_in[14];
    const float* b_out    = (const float*)d_in[15];
    float* out = (float*)d_out;

    // Workspace layout (byte offsets, MB). Total 90 MB.
    //  0-16 : x_bf (dead after down-GEMM) / vt (written by up-GEMM V-epilogue)
    // 16-24 : lat fused [4096][1024] bf16 (dead after up-GEMMs)
    // 16-32 : attn_bf (written by flash; overlays lat + wd_t + wkvu_t, all dead)
    // 24-28 : wd_t fused [1024][2048]
    // 28-32 : wkvu_t   32-34 : wqu_t   34-42 : wout_t
    // 42-58 : q_bf     58-74 : k_bf [4096][2048] (compact K, V fused to vt)
    char* ws = (char*)d_ws;
    u16* x_bf    = (u16*)(ws);
    u16* vt      = (u16*)(ws);
    u16* lat     = (u16*)(ws + (16u << 20));
    u16* attn_bf = (u16*)(ws + (16u << 20));
    u16* wd_t    = (u16*)(ws + (24u << 20));
    u16* wkvu_t  = (u16*)(ws + (28u << 20));
    u16* wqu_t   = (u16*)(ws + (32u << 20));
    u16* wout_t  = (u16*)(ws + (34u << 20));
    u16* q_bf    = (u16*)(ws + (42u << 20));
    u16* k_bf    = (u16*)(ws + (58u << 20));

    const int M = B_ * S_;  // 4096
    dim3 blk(256);

    // prep: x cast + all 5 weight transposes in one launch
    prep_kernel<<<10496, blk, 0, stream>>>(
        wq_down, wkv_down, wq_up, wkv_up, w_out, x,
        wd_t, wqu_t, wkvu_t, wout_t, x_bf);

    // fused down-projection: [M,2048] @ [2048,1024] -> lat (q | kv), BN=64
    gemm_mfma_kernel<u16, 64><<<dim3((2 * L_) / 64, M / 128), blk, 0, stream>>>(
        x_bf, wd_t, bq_down, bkv_down, lat,
        M, 2 * L_, D_, D_, 2 * L_, L_);

    // fused LayerNorm over both halves
    layernorm_fused_kernel<<<2 * M, blk, 0, stream>>>(lat, gq_ln, bq_ln, gkv_ln, bkv_ln);

    // merged up-projections: kv-up (with fused V transpose) + q-up
    up_gemm_kernel<<<dim3(48, M / 128), blk, 0, stream>>>(
        lat, wkvu_t, wqu_t, bkv_up, bq_up, k_bf, vt, q_bf);

    // Flash attention v10 -> bf16 attn
    flash_attn_kernel<<<dim3((S_ / 64) * H_ * B_), blk, 0, stream>>>(
        q_bf, k_bf, vt, mask, attn_bf);

    // Output projection (fp32 out)
    gemm_mfma_kernel<float, 128><<<dim3(D_ / 128, M / 128), blk, 0, stream>>>(
        attn_bf, wout_t, b_out, b_out, out,
        M, D_, D_, D_, D_, D_);
}